// Round 5
// baseline (238.950 us; speedup 1.0000x reference)
//
#include <hip/hip_runtime.h>

#define NB   32
#define NCI  128
#define NH   64
#define NW   64
#define NCO  256
#define NOH  62
#define NOW  62

typedef __attribute__((ext_vector_type(8))) short bf16x8;           // 8 bf16 (4 VGPRs)
typedef __attribute__((ext_vector_type(8))) unsigned short u16x8;
typedef __attribute__((ext_vector_type(4))) float f32x4;

typedef __attribute__((address_space(1))) const unsigned int glb_u32_t;
typedef __attribute__((address_space(3))) unsigned int lds_u32_t;

// fp32 -> bf16 bits, round-to-nearest-even (finite inputs)
__device__ __forceinline__ unsigned short f2bf(float f) {
  unsigned int u = __float_as_uint(f);
  u = u + 0x7FFFu + ((u >> 16) & 1u);
  return (unsigned short)(u >> 16);
}

__device__ __forceinline__ void gload_lds16(const unsigned short* g, unsigned short* l) {
  __builtin_amdgcn_global_load_lds((glb_u32_t*)g, (lds_u32_t*)l, 16, 0, 0);
}

// x[b][ci][h][w] fp32 -> xt[b][h][w][ci] bf16, transposed through LDS.
// One block per (b,h). Writes: coalesced u16x8. LDS pitch 130 elems
// (65 dwords, odd -> conflict-free ds_write_b16 transpose writes).
__global__ __launch_bounds__(256) void cvt_x_kernel(const float* __restrict__ x,
                                                    unsigned short* __restrict__ xt) {
  __shared__ unsigned short l[64 * 130];   // 16640 B
  const int tid = threadIdx.x;
  const int b = blockIdx.x >> 6, h = blockIdx.x & 63;
  const int w0 = tid & 63, c0 = tid >> 6;
  const float* src = x + ((size_t)b * NCI * NH + h) * NW;
  #pragma unroll
  for (int g = 0; g < 32; ++g) {
    int ci = g * 4 + c0;
    l[w0 * 130 + ci] = f2bf(src[(size_t)ci * (NH * NW) + w0]);
  }
  __syncthreads();
  unsigned short* dst = xt + ((size_t)b * NH + h) * NW * NCI;
  #pragma unroll
  for (int it = 0; it < 4; ++it) {
    int gidx = it * 2048 + tid * 8;
    int w = gidx >> 7, ci0 = gidx & 127;
    const unsigned int* lw = (const unsigned int*)(l + w * 130 + ci0);
    union { u16x8 v; unsigned int u[4]; } t;
    t.u[0] = lw[0]; t.u[1] = lw[1]; t.u[2] = lw[2]; t.u[3] = lw[3];
    *(u16x8*)(dst + w * NCI + ci0) = t.v;
  }
}

// W[co][ci][kh][kw] fp32 -> wt[k][co][ci] bf16, coalesced 16B stores
__global__ __launch_bounds__(256) void cvt_w_kernel(const float* __restrict__ wsrc,
                                                    unsigned short* __restrict__ wt) {
  int t = blockIdx.x * 256 + threadIdx.x;            // 0 .. 9*256*16-1
  int oc = t & 15, co = (t >> 4) & 255, k = t >> 12;
  const float* src = wsrc + ((size_t)co * NCI + oc * 8) * 9 + k;
  u16x8 v;
  #pragma unroll
  for (int j = 0; j < 8; ++j) v[j] = f2bf(src[j * 9]);
  *(u16x8*)(wt + ((size_t)k * NCO + co) * NCI + oc * 8) = v;
}

// Implicit direct conv, bf16 MFMA 16x16x32.
// Block: 256 thr (4 waves, 2 wm x 2 wn), tile 128 cout x (2 oh x 64 ow).
// Weights: NO LDS -- af fragments loaded global->VGPR (wt is 0.59 MB,
// L1/L2-resident; per-tap slice 8 KB lives in L1). Only xs (input) is LDS,
// double-buffered; ONE barrier per ci-chunk (4 total), 144 MFMA/wave between
// barriers -> the vmcnt(0) barrier-drain is amortized 9x vs round 2/4.
// xs octet swizzle baked into gload_lds SOURCE (LDS dest linear); same XOR
// on the ds_read side. Buffers padded: kw-tail reads (masked outputs) reach
// ~128B past a buffer and must stay inside the LDS allocation.
__global__ __launch_bounds__(256, 3) void conv_mfma_kernel(
    const unsigned short* __restrict__ xt, const unsigned short* __restrict__ wt,
    const float* __restrict__ bias, float* __restrict__ out) {
  __shared__ unsigned short smem[2 * (4 * 64 * 32) + 512];   // 33792 B
  unsigned short* xsb[2] = { smem, smem + 4 * 64 * 32 };

  const int tid  = threadIdx.x;
  const int lane = tid & 63;
  const int wid  = tid >> 6;
  const int wm   = wid & 1;     // cout half (64)
  const int wn   = wid >> 1;    // output row within pair
  const int l15  = lane & 15;
  const int lo   = lane >> 4;   // k-octet group

  // XCD-bijective swizzle: grid 1984 = 8 * 248 exactly.
  const int bid0  = blockIdx.x;
  const int bid   = (bid0 & 7) * 248 + (bid0 >> 3);
  const int coutg = bid & 1;              // ((b*31 + ohg)*2 + coutg)
  const int ohg   = (bid >> 1) % 31;
  const int b     = bid / 62;
  const int cbase = coutg * 128;
  const int oh0   = ohg * 2;

  f32x4 acc[4][4];
  #pragma unroll
  for (int mi = 0; mi < 4; ++mi)
    #pragma unroll
    for (int ni = 0; ni < 4; ++ni)
      acc[mi][ni] = (f32x4){0.f, 0.f, 0.f, 0.f};

  const size_t xbase = (size_t)b * NH * NW * NCI;

  // per-lane weight base: row (cbase + wm*64 + l15), octet lo
  const unsigned short* wlane = wt + ((size_t)(cbase + wm * 64 + l15)) * NCI + lo * 8;

  // stage xs for ci-chunk cic into buffer cic&1 (16 gload_lds, 4/wave)
  auto stage_x = [&](int cic) {
    unsigned short* dst = xsb[cic & 1];
    #pragma unroll
    for (int i = 0; i < 4; ++i) {
      int e = wid * 4 + i;                 // 0..15
      int u = e * 64 + lane;               // 0..1023
      int o = u & 3, w = (u >> 2) & 63, r = u >> 8;   // r 0..3 (oh0+3 <= 63)
      const unsigned short* src = xt + xbase
          + ((size_t)(oh0 + r) * NW + w) * NCI + cic * 32
          + (o ^ ((w >> 1) & 3)) * 8;
      gload_lds16(src, dst + e * 512);
    }
  };

  // prologue
  stage_x(0);
  __syncthreads();   // drain + barrier

  #pragma unroll
  for (int cic = 0; cic < 4; ++cic) {
    unsigned short* xs = xsb[cic & 1];
    #pragma unroll
    for (int tap = 0; tap < 9; ++tap) {
      const int kh = tap / 3, kw = tap % 3;
      const int r = wn + kh;               // staged input row index 0..3

      // issue next chunk's staging mid-loop: later vmcnt waits (for af loads)
      // then find it already landed; barrier drain at chunk end is ~free.
      if (tap == 4 && cic < 3) stage_x(cic + 1);

      // A fragments: weights straight from global (L1-resident slice)
      bf16x8 af[4], bfv[4];
      const unsigned short* wtap = wlane + ((size_t)tap * NCO) * NCI + cic * 32;
      #pragma unroll
      for (int mi = 0; mi < 4; ++mi)
        af[mi] = *(const bf16x8*)(wtap + (size_t)(mi * 16) * NCI);

      // B fragments: input from swizzled LDS
      #pragma unroll
      for (int ni = 0; ni < 4; ++ni) {
        int w = ni * 16 + l15 + kw;        // up to 65 -> padded-garbage reads,
        bfv[ni] = *(const bf16x8*)(xs +    // feed masked outputs only
            ((size_t)((r * 64 + w) * 4 + (lo ^ ((w >> 1) & 3))) * 8));
      }

      #pragma unroll
      for (int mi = 0; mi < 4; ++mi)
        #pragma unroll
        for (int ni = 0; ni < 4; ++ni)
          acc[mi][ni] = __builtin_amdgcn_mfma_f32_16x16x32_bf16(
              af[mi], bfv[ni], acc[mi][ni], 0, 0, 0);
    }
    // swap xs buffers; drain covers stage_x issued 4-5 taps (~1500 cyc) ago
    __syncthreads();
  }

  // epilogue: D row = (lane>>4)*4 + reg (cout), col = lane&15 (ow)
  const int oh = oh0 + wn;
  #pragma unroll
  for (int mi = 0; mi < 4; ++mi) {
    int co0 = cbase + wm * 64 + mi * 16 + lo * 4;
    const f32x4 bv = *(const f32x4*)(bias + co0);
    #pragma unroll
    for (int ni = 0; ni < 4; ++ni) {
      int ow = ni * 16 + l15;
      if (ow < NOW) {
        size_t o0 = (((size_t)b * NCO + co0) * NOH + oh) * NOW + ow;
        const size_t cs = (size_t)NOH * NOW;
        out[o0]          = acc[mi][ni][0] + bv[0];
        out[o0 + cs]     = acc[mi][ni][1] + bv[1];
        out[o0 + 2 * cs] = acc[mi][ni][2] + bv[2];
        out[o0 + 3 * cs] = acc[mi][ni][3] + bv[3];
      }
    }
  }
}

// Safety-net: correct fp32 direct conv (used only if ws_size too small)
__global__ __launch_bounds__(256) void conv_naive_kernel(
    const float* __restrict__ x, const float* __restrict__ w,
    const float* __restrict__ bias, float* __restrict__ out) {
  long t = (long)blockIdx.x * 256 + threadIdx.x;
  const long total = (long)NB * NCO * NOH * NOW;
  if (t >= total) return;
  int ow = (int)(t % NOW);
  int oh = (int)((t / NOW) % NOH);
  int co = (int)((t / ((long)NOW * NOH)) % NCO);
  int b  = (int)(t / ((long)NOW * NOH * NCO));
  float acc = bias[co];
  for (int ci = 0; ci < NCI; ++ci) {
    const float* xp = x + (((size_t)b * NCI + ci) * NH + oh) * NW + ow;
    const float* wp = w + ((size_t)co * NCI + ci) * 9;
    #pragma unroll
    for (int kh = 0; kh < 3; ++kh)
      #pragma unroll
      for (int kw = 0; kw < 3; ++kw)
        acc += xp[kh * NW + kw] * wp[kh * 3 + kw];
  }
  out[t] = acc;
}

extern "C" void kernel_launch(void* const* d_in, const int* in_sizes, int n_in,
                              void* d_out, int out_size, void* d_ws, size_t ws_size,
                              hipStream_t stream) {
  const float* x    = (const float*)d_in[0];
  const float* w    = (const float*)d_in[1];
  const float* bias = (const float*)d_in[2];
  float* out        = (float*)d_out;

  const size_t WT_BYTES = (size_t)9 * NCO * NCI * 2;             // 589824
  const size_t XT_BYTES = (size_t)NB * NH * NW * NCI * 2;        // 33554432

  if (ws_size >= WT_BYTES + XT_BYTES) {
    unsigned short* wt = (unsigned short*)d_ws;
    unsigned short* xt = (unsigned short*)((char*)d_ws + WT_BYTES);
    cvt_w_kernel<<<(9 * NCO * 16) / 256, 256, 0, stream>>>(w, wt);
    cvt_x_kernel<<<NB * NH, 256, 0, stream>>>(x, xt);
    conv_mfma_kernel<<<2 * 31 * NB, 256, 0, stream>>>(xt, wt, bias, out);
  } else {
    const long total = (long)NB * NCO * NOH * NOW;
    conv_naive_kernel<<<(int)((total + 255) / 256), 256, 0, stream>>>(x, w, bias, out);
  }
}

// Round 6
// 102.212 us; speedup vs baseline: 2.3378x; 2.3378x over previous
//
#include <hip/hip_runtime.h>

#define NB   32
#define NCI  128
#define NH   64
#define NW   64
#define NCO  256
#define NOH  62
#define NOW  62

typedef __attribute__((ext_vector_type(8))) short bf16x8;           // 8 bf16 (4 VGPRs)
typedef __attribute__((ext_vector_type(8))) unsigned short u16x8;
typedef __attribute__((ext_vector_type(4))) float f32x4;

typedef __attribute__((address_space(1))) const unsigned int glb_u32_t;
typedef __attribute__((address_space(3))) unsigned int lds_u32_t;

// fp32 -> bf16 bits, round-to-nearest-even (finite inputs)
__device__ __forceinline__ unsigned short f2bf(float f) {
  unsigned int u = __float_as_uint(f);
  u = u + 0x7FFFu + ((u >> 16) & 1u);
  return (unsigned short)(u >> 16);
}

__device__ __forceinline__ void gload_lds16(const unsigned short* g, unsigned short* l) {
  __builtin_amdgcn_global_load_lds((glb_u32_t*)g, (lds_u32_t*)l, 16, 0, 0);
}

// x[b][ci][h][w] fp32 -> xt[b][h][w][ci] bf16, transposed through LDS.
__global__ __launch_bounds__(256) void cvt_x_kernel(const float* __restrict__ x,
                                                    unsigned short* __restrict__ xt) {
  __shared__ unsigned short l[64 * 130];   // 16640 B
  const int tid = threadIdx.x;
  const int b = blockIdx.x >> 6, h = blockIdx.x & 63;
  const int w0 = tid & 63, c0 = tid >> 6;
  const float* src = x + ((size_t)b * NCI * NH + h) * NW;
  #pragma unroll
  for (int g = 0; g < 32; ++g) {
    int ci = g * 4 + c0;
    l[w0 * 130 + ci] = f2bf(src[(size_t)ci * (NH * NW) + w0]);
  }
  __syncthreads();
  unsigned short* dst = xt + ((size_t)b * NH + h) * NW * NCI;
  #pragma unroll
  for (int it = 0; it < 4; ++it) {
    int gidx = it * 2048 + tid * 8;
    int w = gidx >> 7, ci0 = gidx & 127;
    const unsigned int* lw = (const unsigned int*)(l + w * 130 + ci0);
    union { u16x8 v; unsigned int u[4]; } t;
    t.u[0] = lw[0]; t.u[1] = lw[1]; t.u[2] = lw[2]; t.u[3] = lw[3];
    *(u16x8*)(dst + w * NCI + ci0) = t.v;
  }
}

// W[co][ci][kh][kw] fp32 -> wt[k][co][ci] bf16, coalesced 16B stores
__global__ __launch_bounds__(256) void cvt_w_kernel(const float* __restrict__ wsrc,
                                                    unsigned short* __restrict__ wt) {
  int t = blockIdx.x * 256 + threadIdx.x;            // 0 .. 9*256*16-1
  int oc = t & 15, co = (t >> 4) & 255, k = t >> 12;
  const float* src = wsrc + ((size_t)co * NCI + oc * 8) * 9 + k;
  u16x8 v;
  #pragma unroll
  for (int j = 0; j < 8; ++j) v[j] = f2bf(src[j * 9]);
  *(u16x8*)(wt + ((size_t)k * NCO + co) * NCI + oc * 8) = v;
}

// Implicit direct conv, bf16 MFMA 16x16x32 — round-2 geometry + T4 counted
// vmcnt + T5 setprio.
// Block: 256 thr (4 waves, 2 wm x 2 wn), tile 128 cout x (2 oh x 64 ow).
// 12 steps (s = cic*3+kh), ws staged per-kh (24 KB), xs per-cic (16 KB),
// both double-buffered: LDS 80 KB -> 2 blocks/CU (the independent-block TLP
// that round 3/4 lost). Barrier structure per step:
//   stage(s+1) issue -> s_waitcnt vmcnt(K_{s+1}) [step-s loads landed,
//   step-(s+1) loads STAY IN FLIGHT across the barrier] -> s_barrier ->
//   compute(s) -> s_barrier [WAR fence for parity reuse].
// Never vmcnt(0) in the main loop (T4, m218). sched_barrier(0) after each
// barrier blocks ds_read hoist/sink across it (m214 r263).
// Octet swizzle baked into gload_lds SOURCE (LDS dest linear); same XOR on
// read. xs w=64..65 overreads land in the following ws region (in-bounds,
// masked outputs only); ws reads end exactly at buffer end.
__global__ __launch_bounds__(256, 2) void conv_mfma_kernel(
    const unsigned short* __restrict__ xt, const unsigned short* __restrict__ wt,
    const float* __restrict__ bias, float* __restrict__ out) {
  __shared__ unsigned short smem[2 * (4 * 64 * 32) + 2 * (3 * 128 * 32)];  // 81920 B
  unsigned short* xsb[2] = { smem, smem + 4 * 64 * 32 };
  unsigned short* wsb[2] = { smem + 2 * 4 * 64 * 32,
                             smem + 2 * 4 * 64 * 32 + 3 * 128 * 32 };

  const int tid  = threadIdx.x;
  const int lane = tid & 63;
  const int wid  = tid >> 6;
  const int wm   = wid & 1;     // cout half (64)
  const int wn   = wid >> 1;    // output row within pair
  const int l15  = lane & 15;
  const int lo   = lane >> 4;   // k-octet group

  // XCD-bijective swizzle: grid 1984 = 8 * 248 exactly.
  const int bid0  = blockIdx.x;
  const int bid   = (bid0 & 7) * 248 + (bid0 >> 3);
  const int coutg = bid & 1;              // ((b*31 + ohg)*2 + coutg)
  const int ohg   = (bid >> 1) % 31;
  const int b     = bid / 62;
  const int cbase = coutg * 128;
  const int oh0   = ohg * 2;

  f32x4 acc[4][4];
  #pragma unroll
  for (int mi = 0; mi < 4; ++mi)
    #pragma unroll
    for (int ni = 0; ni < 4; ++ni)
      acc[mi][ni] = (f32x4){0.f, 0.f, 0.f, 0.f};

  const size_t xbase = (size_t)b * NH * NW * NCI;

  // stage xs for ci-chunk cic into buffer cic&1 (16 gload_lds, 4/wave)
  auto stage_x = [&](int cic) {
    unsigned short* dst = xsb[cic & 1];
    #pragma unroll
    for (int i = 0; i < 4; ++i) {
      int e = wid * 4 + i;
      int u = e * 64 + lane;
      int o = u & 3, w = (u >> 2) & 63, r = u >> 8;   // r 0..3 (oh0+3 <= 63)
      const unsigned short* src = xt + xbase
          + ((size_t)(oh0 + r) * NW + w) * NCI + cic * 32
          + (o ^ ((w >> 1) & 3)) * 8;
      gload_lds16(src, dst + e * 512);
    }
  };

  // stage ws for step s = cic*3+kh into buffer s&1 (24 gload_lds, 6/wave)
  auto stage_w = [&](int s) {
    int cic = s / 3, kh = s % 3;
    unsigned short* dst = wsb[s & 1];
    #pragma unroll
    for (int i = 0; i < 6; ++i) {
      int e = wid * 6 + i;
      int v = e * 64 + lane;
      int o = v & 3, co = (v >> 2) & 127, kw = v >> 9;
      const unsigned short* src = wt
          + ((size_t)(kh * 3 + kw) * NCO + cbase + co) * NCI + cic * 32
          + (o ^ ((co >> 1) & 3)) * 8;
      gload_lds16(src, dst + e * 512);
    }
  };

  // prologue: fill pipeline stage 0 (10 loads/wave), full drain once
  stage_w(0);
  stage_x(0);
  asm volatile("s_waitcnt vmcnt(0)" ::: "memory");
  __builtin_amdgcn_s_barrier();
  __builtin_amdgcn_sched_barrier(0);

  #pragma unroll
  for (int s = 0; s < 12; ++s) {
    const int cic = s / 3, kh = s % 3;

    // issue next step's staging (writes OTHER parity; safe: barrier #2 of
    // step s-1 fenced all reads of that parity), then counted wait: the K
    // loads just issued may remain outstanding, step-s loads (older) retire.
    if (s < 11) {
      stage_w(s + 1);
      if ((s + 1) % 3 == 0) {
        stage_x((s + 1) / 3);
        asm volatile("s_waitcnt vmcnt(10)" ::: "memory");
      } else {
        asm volatile("s_waitcnt vmcnt(6)" ::: "memory");
      }
    } else {
      asm volatile("s_waitcnt vmcnt(0)" ::: "memory");
    }
    __builtin_amdgcn_s_barrier();          // everyone's step-s data in LDS
    __builtin_amdgcn_sched_barrier(0);

    // compute step s from current-parity buffers
    {
      unsigned short* xs = xsb[cic & 1];
      unsigned short* ws = wsb[s & 1];
      const int r = wn + kh;               // staged input row index 0..3
      #pragma unroll
      for (int kw = 0; kw < 3; ++kw) {
        bf16x8 af[4], bfv[4];
        #pragma unroll
        for (int mi = 0; mi < 4; ++mi) {
          int co = wm * 64 + mi * 16 + l15;
          af[mi] = *(const bf16x8*)(ws +
              ((size_t)((kw * 128 + co) * 4 + (lo ^ ((co >> 1) & 3))) * 8));
        }
        #pragma unroll
        for (int ni = 0; ni < 4; ++ni) {
          int w = ni * 16 + l15 + kw;      // up to 65 -> lands in ws region,
          bfv[ni] = *(const bf16x8*)(xs +  // masked outputs only
              ((size_t)((r * 64 + w) * 4 + (lo ^ ((w >> 1) & 3))) * 8));
        }
        __builtin_amdgcn_s_setprio(1);     // T5: favor MFMA-entering wave
        #pragma unroll
        for (int mi = 0; mi < 4; ++mi)
          #pragma unroll
          for (int ni = 0; ni < 4; ++ni)
            acc[mi][ni] = __builtin_amdgcn_mfma_f32_16x16x32_bf16(
                af[mi], bfv[ni], acc[mi][ni], 0, 0, 0);
        __builtin_amdgcn_s_setprio(0);
      }
    }

    // WAR fence: all waves' ds_reads of this parity consumed (compiler
    // inserts lgkmcnt before MFMA use) before next iter restages it.
    if (s < 11) {
      __builtin_amdgcn_s_barrier();
      __builtin_amdgcn_sched_barrier(0);
    }
  }

  // epilogue: D row = (lane>>4)*4 + reg (cout), col = lane&15 (ow)
  const int oh = oh0 + wn;
  #pragma unroll
  for (int mi = 0; mi < 4; ++mi) {
    int co0 = cbase + wm * 64 + mi * 16 + lo * 4;
    const f32x4 bv = *(const f32x4*)(bias + co0);
    #pragma unroll
    for (int ni = 0; ni < 4; ++ni) {
      int ow = ni * 16 + l15;
      if (ow < NOW) {
        size_t o0 = (((size_t)b * NCO + co0) * NOH + oh) * NOW + ow;
        const size_t cs = (size_t)NOH * NOW;
        out[o0]          = acc[mi][ni][0] + bv[0];
        out[o0 + cs]     = acc[mi][ni][1] + bv[1];
        out[o0 + 2 * cs] = acc[mi][ni][2] + bv[2];
        out[o0 + 3 * cs] = acc[mi][ni][3] + bv[3];
      }
    }
  }
}

// Safety-net: correct fp32 direct conv (used only if ws_size too small)
__global__ __launch_bounds__(256) void conv_naive_kernel(
    const float* __restrict__ x, const float* __restrict__ w,
    const float* __restrict__ bias, float* __restrict__ out) {
  long t = (long)blockIdx.x * 256 + threadIdx.x;
  const long total = (long)NB * NCO * NOH * NOW;
  if (t >= total) return;
  int ow = (int)(t % NOW);
  int oh = (int)((t / NOW) % NOH);
  int co = (int)((t / ((long)NOW * NOH)) % NCO);
  int b  = (int)(t / ((long)NOW * NOH * NCO));
  float acc = bias[co];
  for (int ci = 0; ci < NCI; ++ci) {
    const float* xp = x + (((size_t)b * NCI + ci) * NH + oh) * NW + ow;
    const float* wp = w + ((size_t)co * NCI + ci) * 9;
    #pragma unroll
    for (int kh = 0; kh < 3; ++kh)
      #pragma unroll
      for (int kw = 0; kw < 3; ++kw)
        acc += xp[kh * NW + kw] * wp[kh * 3 + kw];
  }
  out[t] = acc;
}

extern "C" void kernel_launch(void* const* d_in, const int* in_sizes, int n_in,
                              void* d_out, int out_size, void* d_ws, size_t ws_size,
                              hipStream_t stream) {
  const float* x    = (const float*)d_in[0];
  const float* w    = (const float*)d_in[1];
  const float* bias = (const float*)d_in[2];
  float* out        = (float*)d_out;

  const size_t WT_BYTES = (size_t)9 * NCO * NCI * 2;             // 589824
  const size_t XT_BYTES = (size_t)NB * NH * NW * NCI * 2;        // 33554432

  if (ws_size >= WT_BYTES + XT_BYTES) {
    unsigned short* wt = (unsigned short*)d_ws;
    unsigned short* xt = (unsigned short*)((char*)d_ws + WT_BYTES);
    cvt_w_kernel<<<(9 * NCO * 16) / 256, 256, 0, stream>>>(w, wt);
    cvt_x_kernel<<<NB * NH, 256, 0, stream>>>(x, xt);
    conv_mfma_kernel<<<2 * 31 * NB, 256, 0, stream>>>(xt, wt, bias, out);
  } else {
    const long total = (long)NB * NCO * NOH * NOW;
    conv_naive_kernel<<<(int)((total + 255) / 256), 256, 0, stream>>>(x, w, bias, out);
  }
}